// Round 6
// baseline (354.165 us; speedup 1.0000x reference)
//
#include <hip/hip_runtime.h>

// Problem constants
#define RED    100000   // reduction dim = C*RF*L = 1*50*2000
#define TT     32       // timesteps (M)
#define KF     512      // features (N)
#define THRESH 10.0f
#define KWTA   16

// GEMM tiling
#define CHUNKS 125      // red-dim split
#define CHUNK  800      // 125*800 = 100000
#define RB     32       // red elems per LDS stage
#define NSTAGE 25       // CHUNK/RB
#define TNK    128      // k-tile width
#define NKT    4        // KF/TNK
#define KK     4        // k-columns per thread (16B A-read feeds 16 FMAs)

// ---------------------------------------------------------------------------
// K1: split-K GEMM, M-in-registers. Thread = (kg 0..31, slot 0..7); owns
// k-cols {kg, kg+32, kg+64, kg+96} of a TNK=128 tile and all 32 timesteps:
// acc[32][4] (128 VGPRs). A double-buffered in LDS (2x4KB), ONE barrier per
// stage. B streamed global->register. Per stage/lane: 32 ds_read_b128 +
// 4 global b128 for 512 FMAs (1 B LDS per FMA).
// CRITICAL (R2/R3 lesson): every acc[] index must be compile-time, else the
// array goes to scratch (was 1.25 GB WRITE_SIZE, 325 us).
// ---------------------------------------------------------------------------
template <int ATOMIC>
__global__ __launch_bounds__(256, 2)
void gemm_k(const float* __restrict__ rec, const float* __restrict__ wgt,
            float* __restrict__ dst) {
  __shared__ float Al[2][TT][RB];   // 8 KB, double-buffered A tile [t][r]

  const int chunk = blockIdx.x;  // 0..124
  const int kt    = blockIdx.y;  // 0..3
  const int tid   = threadIdx.x;
  const int kg    = tid >> 3;    // 0..31  (also A-staging row)
  const int slot  = tid & 7;     // 0..7   (4-float red slot)

  const float* ap = rec + (size_t)kg * RED + chunk * CHUNK + slot * 4;
  const float* bp = wgt + (size_t)(kt * TNK + kg) * RED + chunk * CHUNK + slot * 4;
  const size_t bs = (size_t)32 * RED;   // k -> k+32

  float acc[TT][KK];
#pragma unroll
  for (int t = 0; t < TT; ++t)
#pragma unroll
    for (int c = 0; c < KK; ++c) acc[t][c] = 0.f;

  // prologue: stage-0 A + B, stage-1 A in flight
  float4 av = *(const float4*)ap;
  float4 b0 = *(const float4*)bp;
  float4 b1 = *(const float4*)(bp + bs);
  float4 b2 = *(const float4*)(bp + 2 * bs);
  float4 b3 = *(const float4*)(bp + 3 * bs);
  *(float4*)&Al[0][kg][slot * 4] = av;
  ap += RB;
  av = *(const float4*)ap;            // A for stage 1
  __syncthreads();

#pragma unroll 1
  for (int s = 0; s < NSTAGE; ++s) {
    const int cur = s & 1;
    const float4 cb0 = b0, cb1 = b1, cb2 = b2, cb3 = b3;
    if (s + 1 < NSTAGE) {
      *(float4*)&Al[cur ^ 1][kg][slot * 4] = av;   // stage s+1 A
      ap += RB; bp += RB;
      av = *(const float4*)ap;                     // A for s+2
      b0 = *(const float4*)bp;                     // B for s+1
      b1 = *(const float4*)(bp + bs);
      b2 = *(const float4*)(bp + 2 * bs);
      b3 = *(const float4*)(bp + 3 * bs);
    }
#pragma unroll
    for (int t = 0; t < TT; ++t) {
      const float4 a = *(const float4*)&Al[cur][t][slot * 4];  // 8-way bcast
      acc[t][0] = fmaf(a.x, cb0.x, acc[t][0]);
      acc[t][0] = fmaf(a.y, cb0.y, acc[t][0]);
      acc[t][0] = fmaf(a.z, cb0.z, acc[t][0]);
      acc[t][0] = fmaf(a.w, cb0.w, acc[t][0]);
      acc[t][1] = fmaf(a.x, cb1.x, acc[t][1]);
      acc[t][1] = fmaf(a.y, cb1.y, acc[t][1]);
      acc[t][1] = fmaf(a.z, cb1.z, acc[t][1]);
      acc[t][1] = fmaf(a.w, cb1.w, acc[t][1]);
      acc[t][2] = fmaf(a.x, cb2.x, acc[t][2]);
      acc[t][2] = fmaf(a.y, cb2.y, acc[t][2]);
      acc[t][2] = fmaf(a.z, cb2.z, acc[t][2]);
      acc[t][2] = fmaf(a.w, cb2.w, acc[t][2]);
      acc[t][3] = fmaf(a.x, cb3.x, acc[t][3]);
      acc[t][3] = fmaf(a.y, cb3.y, acc[t][3]);
      acc[t][3] = fmaf(a.z, cb3.z, acc[t][3]);
      acc[t][3] = fmaf(a.w, cb3.w, acc[t][3]);
    }
    __syncthreads();   // separates reads of buf[cur] from next stage's write
  }

  // butterfly-reduce the 8 red-slots (lane bits 0..2); all indices static
#pragma unroll
  for (int m = 1; m <= 4; m <<= 1) {
#pragma unroll
    for (int t = 0; t < TT; ++t)
#pragma unroll
      for (int c = 0; c < KK; ++c)
        acc[t][c] += __shfl_xor(acc[t][c], m, 64);
  }

  // epilogue: one writer per (t,kg): lane with slot == t>>2 (static acc idx)
  if (ATOMIC) {
#pragma unroll
    for (int t = 0; t < TT; ++t) {
      if (slot == (t >> 2)) {
#pragma unroll
        for (int c = 0; c < KK; ++c)
          atomicAdd(&dst[t * KF + kt * TNK + kg + 32 * c], acc[t][c]);
      }
    }
  } else {
    float* p = dst + (size_t)(chunk * NKT + kt) * TT * TNK;
#pragma unroll
    for (int t = 0; t < TT; ++t) {
      if (slot == (t >> 2)) {
#pragma unroll
        for (int c = 0; c < KK; ++c)
          p[t * TNK + kg + 32 * c] = acc[t][c];
      }
    }
  }
}

// ---------------------------------------------------------------------------
// K2: reduce 125 partial tiles -> om[32][512]; layout [chunk][kt][t][kk]
// ---------------------------------------------------------------------------
__global__ __launch_bounds__(256)
void reduce_k(const float* __restrict__ part, float* __restrict__ om) {
  const int i  = blockIdx.x * 256 + threadIdx.x;  // 0..16383
  const int t  = i >> 9;
  const int k  = i & 511;
  const int kt = k >> 7;         // TNK=128
  const int kk = k & 127;
  const float* p = part + (size_t)kt * TT * TNK + (size_t)t * TNK + kk;
  float s = 0.f;
#pragma unroll 5
  for (int c = 0; c < CHUNKS; ++c) s += p[(size_t)c * NKT * TT * TNK];
  om[i] = s;
}

// ---------------------------------------------------------------------------
// K3: threshold / nspk / first-spike value / v / total / 16x KWTA argmax
// (wave shfl_xor reductions, lowest-index tie-break) / final sign mask.
// om aliases d_out (fully overwritten, read-before-write per element).
// ---------------------------------------------------------------------------
__global__ __launch_bounds__(512)
void kwta_k(const float* __restrict__ om, float* __restrict__ out) {
  __shared__ float tot[KF];
  __shared__ float coef[KF];
  __shared__ float wmax[8];
  __shared__ int   widx[8];
  __shared__ float bflag;
  const int k    = threadIdx.x;   // feature
  const int lane = k & 63;
  const int wv   = k >> 6;

  int ns = 0;
#pragma unroll
  for (int t = 0; t < TT; ++t) ns += (om[t * KF + k] > THRESH) ? 1 : 0;
  int first = TT - ns;
  if (first > TT - 1) first = TT - 1;
  float pf = om[first * KF + k];
  pf = (pf > THRESH) ? pf : 0.0f;

  // v = max_k(values * sign(nspk)) * T
  float m = (ns > 0) ? pf : 0.0f;
#pragma unroll
  for (int off = 1; off <= 32; off <<= 1) m = fmaxf(m, __shfl_xor(m, off, 64));
  if (lane == 0) wmax[wv] = m;
  __syncthreads();
  float v = wmax[0];
#pragma unroll
  for (int w = 1; w < 8; ++w) v = fmaxf(v, wmax[w]);
  v *= (float)TT;

  const float t1 = (float)ns * pf;
  const float t2 = (float)ns * v;
  tot[k]  = t1 + t2;                   // >= 0 always
  coef[k] = 0.0f;
  __syncthreads();

  for (int it = 0; it < KWTA; ++it) {
    float val = tot[k];
    int   idx = k;
#pragma unroll
    for (int off = 1; off <= 32; off <<= 1) {
      const float ov = __shfl_xor(val, off, 64);
      const int   oi = __shfl_xor(idx, off, 64);
      if (ov > val || (ov == val && oi < idx)) { val = ov; idx = oi; }
    }
    if (lane == 0) { wmax[wv] = val; widx[wv] = idx; }
    __syncthreads();
    if (k == 0) {
      float bv = wmax[0]; int bi = widx[0];
#pragma unroll
      for (int w = 1; w < 8; ++w)
        if (wmax[w] > bv || (wmax[w] == bv && widx[w] < bi)) { bv = wmax[w]; bi = widx[w]; }
      if (bv != 0.0f) { tot[bi] = 0.0f; coef[bi] = 1.0f; bflag = 1.0f; }
      else            { bflag = 0.0f; }
    }
    __syncthreads();
    if (bflag == 0.0f) break;          // uniform: remaining winners = -1
  }
  __syncthreads();

  // out = sign(pot * coef); each element read-then-written by its own thread
  for (int i = k; i < TT * KF; i += KF) {
    const int kk = i & 511;
    const float p = om[i];
    out[i] = (p > THRESH && coef[kk] != 0.0f) ? 1.0f : 0.0f;
  }
}

// ---------------------------------------------------------------------------
extern "C" void kernel_launch(void* const* d_in, const int* in_sizes, int n_in,
                              void* d_out, int out_size, void* d_ws, size_t ws_size,
                              hipStream_t stream) {
  const float* rec = (const float*)d_in[0];   // (32,1,50,2000)
  const float* wgt = (const float*)d_in[1];   // (512,1,50,2000)
  float* out = (float*)d_out;                 // 16384 floats
  float* om  = (float*)d_out;                 // out-matrix aliases d_out
  const size_t part_bytes = (size_t)CHUNKS * NKT * TT * TNK * sizeof(float); // 8.192 MB

  if (ws_size >= part_bytes) {
    float* part = (float*)d_ws;
    gemm_k<0><<<dim3(CHUNKS, NKT), 256, 0, stream>>>(rec, wgt, part);
    reduce_k<<<(TT * KF) / 256, 256, 0, stream>>>(part, om);
  } else {
    hipMemsetAsync(om, 0, (size_t)TT * KF * sizeof(float), stream);
    gemm_k<1><<<dim3(CHUNKS, NKT), 256, 0, stream>>>(rec, wgt, om);
  }
  kwta_k<<<1, 512, 0, stream>>>(om, out);
}